// Round 4
// baseline (602.161 us; speedup 1.0000x reference)
//
#include <hip/hip_runtime.h>
#include <math.h>

#define NANG 120
#define NB   16
#define H    50
#define SD   100
#define NBIN 51        // rfft bins of length-100
#define PADB 3         // top pad rows of B-hat
#define BROWS 60       // stored rows: r in [-3, 56]
#define BST  106       // B-hat row stride
#define WST  104       // g_W row stride
#define RTST 52        // Rt row stride
#define CST2 100       // C lag stride (lagIdx 0..99)
#define AX   58        // g_Arec x rows (50 real + 8 zero pad)

// ---- device-global scratch ----
__device__ __align__(16) float g_Arec[NB*2*AX*NBIN*2 + 64]; // [b][c][x][om][2], x 50..57 zero
__device__ __align__(16) float g_ligc[NB*2*H*H];            // [b][c][y][x]
__device__ __align__(16) float g_W[H*WST];                  // [y][2*om+p] = (cos, -sin)
__device__ __align__(16) float g_P[NBIN*128 + 64];          // [om][2*dy+p] = (cos,sin), dy 0..49
__device__ float g_resV[NANG*NB];
__device__ int   g_resP[NANG*NB];

// per-wave tile schedule: d0 values (lag-tile bases), 127 = sentinel.
// step counts (ng*8, both halves): w0 176, w1 184, w2 184, w3 184.
__device__ const int g_schedD[4][7] = {
  {-49, -5, -33,  -1, 19, 47, 127},
  {-45, -9, -29,   3, 15, 39, 127},
  {-41,-13, -25,   7, 11, 43, 127},
  {-37,-17, -21,  23, 27, 31,  35}
};

// ================= prep: conv+relu+combine, rec spectrum, tables =================
__global__ __launch_bounds__(256) void k_prep(const float* __restrict__ rec,
                                              const float* __restrict__ lig,
                                              const float* __restrict__ wr,
                                              const float* __restrict__ br,
                                              const float* __restrict__ wsc) {
  const int blk = blockIdx.x;
  const int tid = threadIdx.x;
  if (blk == NB) {
    for (int u = tid; u < H*WST; u += 256) {
      int y = u / WST, col = u % WST;
      float v = 0.f;
      if (col < 2*NBIN) {
        int om = col >> 1;
        int k = (om * y) % SD;
        double ang = 6.283185307179586 * (double)k / 100.0;
        v = (col & 1) ? (float)(-sin(ang)) : (float)cos(ang);
      }
      g_W[u] = v;
    }
    for (int u = tid; u < NBIN*128; u += 256) {
      int om = u >> 7, q = u & 127;
      int dy = q >> 1;
      float v = 0.f;
      if (dy <= 49) {
        int k = (om * dy) % SD;
        double ang = 6.283185307179586 * (double)k / 100.0;
        v = (q & 1) ? (float)sin(ang) : (float)cos(ang);
      }
      g_P[u] = v;
    }
    return;
  }
  const int b = blk;
  __shared__ float recf[2*H*H];
  __shared__ float tbl[SD*2];
  for (int k = tid; k < SD; k += 256) {
    double ang = 6.283185307179586 * (double)k / 100.0;
    tbl[2*k]   = (float)cos(ang);
    tbl[2*k+1] = (float)sin(ang);
  }
  const float* rimg = rec + b*H*H;
  const float* limg = lig + b*H*H;
  for (int p = tid; p < H*H; p += 256) {
    int i = p / H, j = p - (p/H)*H;
    float ar0 = br[0], ar1 = br[1], al0 = br[0], al1 = br[1];
    for (int di = 0; di < 3; ++di) {
      int ii = i + di - 1;
      if (ii < 0 || ii >= H) continue;
      for (int dj = 0; dj < 3; ++dj) {
        int jj = j + dj - 1;
        if (jj < 0 || jj >= H) continue;
        float rv = rimg[ii*H+jj], lv = limg[ii*H+jj];
        float w0 = wr[di*3 + dj], w1 = wr[9 + di*3 + dj];
        ar0 += w0*rv; ar1 += w1*rv; al0 += w0*lv; al1 += w1*lv;
      }
    }
    ar0 = fmaxf(ar0, 0.f); ar1 = fmaxf(ar1, 0.f);
    al0 = fmaxf(al0, 0.f); al1 = fmaxf(al1, 0.f);
    recf[p] = ar0; recf[H*H + p] = ar1;
    g_ligc[((b*2+0)*H + i)*H + j] = wsc[0]*al0 + wsc[1]*al1;
    g_ligc[((b*2+1)*H + i)*H + j] = wsc[2]*al0 + wsc[3]*al1;
  }
  for (int u = tid; u < 2*8*102; u += 256) {
    int c = u / 816; int r = u % 816;
    int x = 50 + r / 102; int q = r % 102;
    g_Arec[((b*2+c)*AX + x)*102 + q] = 0.f;
  }
  __syncthreads();
  for (int u = tid; u < 2*H*NBIN; u += 256) {
    int om = u % NBIN; int rest = u / NBIN; int x = rest % H; int c = rest / H;
    const float* row = recf + (c*H + x)*H;
    float sr = 0.f, si = 0.f;
    int k = 0;
    for (int y = 0; y < H; ++y) {
      float rv = row[y];
      sr += rv * tbl[2*k];
      si -= rv * tbl[2*k+1];
      k += om; if (k >= SD) k -= SD;
    }
    float* dst = g_Arec + ((b*2+c)*AX + x)*102 + 2*om;
    dst[0] = sr; dst[1] = si;
  }
}

#define P3_STEP(uu) do { \
  float Ar = ar_[(uu)&7], Ai = ai_[(uu)&7]; \
  { const int sl=(uu)&7;     c0 += Ar*br_[sl] + Ai*bi_[sl]; c4 += Ar*bi_[sl] - Ai*br_[sl]; } \
  { const int sl=((uu)+1)&7; c1 += Ar*br_[sl] + Ai*bi_[sl]; c5 += Ar*bi_[sl] - Ai*br_[sl]; } \
  { const int sl=((uu)+2)&7; c2 += Ar*br_[sl] + Ai*bi_[sl]; c6 += Ar*bi_[sl] - Ai*br_[sl]; } \
  { const int sl=((uu)+3)&7; c3 += Ar*br_[sl] + Ai*bi_[sl]; c7 += Ar*bi_[sl] - Ai*br_[sl]; } \
} while(0)

// ================= main: per (angle,batch) block =================
__global__ __launch_bounds__(256, 3) void k_main() {
  const int bid = blockIdx.x;
  const int a = bid % NANG;
  const int b = bid / NANG;
  const int tid = threadIdx.x;

  // LDS union plan (words):
  //   [0..5200)      Rt [2][50][52]        (dead after P2(c=1))
  //   [5200..11560)  sB [60][106]          (dead after P3(c=1))
  //   [0..5100)      Cr [51][100]          (written after both dead)
  //   [5100..10200)  Ci [51][100]
  //   [11560..12072) reduction buffers
  __shared__ __align__(16) float sMem[12072];
  float* Rt = sMem;
  float* sB = sMem + 5200;
  float* Cr = sMem;
  float* Ci = sMem + 5100;
  float* sRedV = sMem + 11560;
  int*   sRedP = (int*)(sMem + 11816);

  // P0: zero pad rows of sB (rows 0..2, 53..59)
  for (int u = tid; u < 10*BST; u += 256) {
    int r = u / BST;
    int row = (r < 3) ? r : r + 50;
    sB[row*BST + (u % BST)] = 0.f;
  }

  // P1: bilinear rotation of combined ligand features -> Rt (transposed)
  float angf = 0.05235987755982988f * (float)a;
  float ca = cosf(angf), sa = sinf(angf);
  const float* L0 = g_ligc + (b*2+0)*H*H;
  const float* L1 = g_ligc + (b*2+1)*H*H;
  for (int p = tid; p < H*H; p += 256) {
    int i = p / H, j = p - (p/H)*H;
    float gy = -1.f + (float)i*(2.f/49.f);
    float gx = -1.f + (float)j*(2.f/49.f);
    float x_in = ca*gx - sa*gy;
    float y_in = sa*gx + ca*gy;
    float px = (x_in + 1.f)*0.5f*49.f;
    float py = (y_in + 1.f)*0.5f*49.f;
    float fx = floorf(px), fy = floorf(py);
    int x0 = (int)fx, y0 = (int)fy;
    int x1 = x0 + 1, y1 = y0 + 1;
    float wx1 = px - fx, wx0 = 1.f - wx1;
    float wy1 = py - fy, wy0 = 1.f - wy1;
    float v0 = 0.f, v1 = 0.f;
    if (y0 >= 0 && y0 < H) {
      if (x0 >= 0 && x0 < H) { float w = wy0*wx0; int o = y0*H+x0; v0 += w*L0[o]; v1 += w*L1[o]; }
      if (x1 >= 0 && x1 < H) { float w = wy0*wx1; int o = y0*H+x1; v0 += w*L0[o]; v1 += w*L1[o]; }
    }
    if (y1 >= 0 && y1 < H) {
      if (x0 >= 0 && x0 < H) { float w = wy1*wx0; int o = y1*H+x0; v0 += w*L0[o]; v1 += w*L1[o]; }
      if (x1 >= 0 && x1 < H) { float w = wy1*wx1; int o = y1*H+x1; v0 += w*L0[o]; v1 += w*L1[o]; }
    }
    Rt[(0*H + j)*RTST + i] = v0;
    Rt[(1*H + j)*RTST + i] = v1;
  }
  __syncthreads();

  const int wid = tid >> 6, lane = tid & 63;
  const int om = (lane <= 50) ? lane : 50;
  const bool omValid = (lane <= 50);

  float acc[7][8];
  #pragma unroll
  for (int s = 0; s < 7; ++s)
    #pragma unroll
    for (int k = 0; k < 8; ++k) acc[s][k] = 0.f;

  for (int c = 0; c < 2; ++c) {
    // P2(c): y-DFT of rotated rows -> sB. Tiles 4 rows x 6 cols, 221 units.
    if (tid < 221) {
      int cg = tid % 17;          // col group, fast across lanes
      int it = tid / 17;          // 0..12
      int i0 = it*4;
      int col0 = 6*cg;
      float pacc[4][6];
      #pragma unroll
      for (int p = 0; p < 4; ++p)
        #pragma unroll
        for (int q = 0; q < 6; ++q) pacc[p][q] = 0.f;
      const float* rtc = Rt + c*H*RTST + i0;
      const float* wt = g_W + col0;
      #pragma unroll 2
      for (int y = 0; y < H; ++y) {
        float4 rv = *(const float4*)&rtc[y*RTST];
        float ww[6];
        #pragma unroll
        for (int q = 0; q < 3; ++q) {
          float2 w2 = *(const float2*)&wt[y*WST + 2*q];
          ww[2*q] = w2.x; ww[2*q+1] = w2.y;
        }
        float rr[4] = {rv.x, rv.y, rv.z, rv.w};
        #pragma unroll
        for (int p = 0; p < 4; ++p)
          #pragma unroll
          for (int q = 0; q < 6; ++q) pacc[p][q] += rr[p]*ww[q];
      }
      float* dst = sB + col0;
      #pragma unroll
      for (int p = 0; p < 4; ++p) {
        int i = i0 + p;
        if (i < H) {
          #pragma unroll
          for (int q = 0; q < 3; ++q) {
            float2 o = {pacc[p][2*q], pacc[p][2*q+1]};
            *(float2*)&dst[(PADB+i)*BST + 2*q] = o;
          }
        }
      }
    }
    __syncthreads();

    // P3(c): per-bin complex correlation along x, accumulate into registers
    #pragma unroll
    for (int slot = 0; slot < 7; ++slot) {
      const int d0 = g_schedD[wid][slot];
      if (d0 != 127) {
        const int x_lo = max(0, -(d0+3));
        const int x_hi = min(H, H - d0);
        const int ng = (x_hi - x_lo + 7) >> 3;
        float c0=acc[slot][0], c1=acc[slot][1], c2=acc[slot][2], c3=acc[slot][3];
        float c4=acc[slot][4], c5=acc[slot][5], c6=acc[slot][6], c7=acc[slot][7];
        const float* Ap = g_Arec + ((b*2+c)*AX + x_lo)*102 + 2*om;
        const float* Bp = sB + (PADB + x_lo + d0)*BST + 2*om;
        float br_[8], bi_[8], ar_[8], ai_[8];
        #pragma unroll
        for (int s = 0; s < 8; ++s) {
          float2 bv = *(const float2*)&Bp[s*BST];
          br_[s] = bv.x; bi_[s] = bv.y;
          float2 av = *(const float2*)&Ap[s*102];
          ar_[s] = av.x; ai_[s] = av.y;
        }
        #pragma unroll 1
        for (int g = 0; g < ng-1; ++g) {
          #pragma unroll
          for (int u = 0; u < 8; ++u) {
            P3_STEP(u);
            float2 bv = *(const float2*)&Bp[(u+8)*BST];
            br_[u] = bv.x; bi_[u] = bv.y;
            float2 av = *(const float2*)&Ap[(u+8)*102];
            ar_[u] = av.x; ai_[u] = av.y;
          }
          Bp += 8*BST; Ap += 8*102;
        }
        {
          const int rowcap = 56 - (x_lo + 8*(ng-1) + d0);
          P3_STEP(0); P3_STEP(1); P3_STEP(2); P3_STEP(3); P3_STEP(4);
          #pragma unroll
          for (int s = 0; s < 3; ++s) {
            int o = min(8+s, rowcap);
            float2 bv = *(const float2*)&Bp[o*BST];
            br_[s] = bv.x; bi_[s] = bv.y;
          }
          P3_STEP(5); P3_STEP(6); P3_STEP(7);
        }
        acc[slot][0]=c0; acc[slot][1]=c1; acc[slot][2]=c2; acc[slot][3]=c3;
        acc[slot][4]=c4; acc[slot][5]=c5; acc[slot][6]=c6; acc[slot][7]=c7;
      }
    }
    __syncthreads();   // sB reads done before next P2 overwrites (or before C stores)
  }

  // store accumulators -> Cr/Ci (overlaps dead Rt/sB regions)
  if (omValid) {
    const float sc = (om == 0 || om == 50) ? 0.5f : 1.0f;
    #pragma unroll
    for (int slot = 0; slot < 7; ++slot) {
      const int d0 = g_schedD[wid][slot];
      if (d0 != 127) {
        int base = om*CST2 + d0 + 49;
        float2 v0 = {acc[slot][0]*sc, acc[slot][1]*sc};
        float2 v1 = {acc[slot][2]*sc, acc[slot][3]*sc};
        float2 v2 = {acc[slot][4]*sc, acc[slot][5]*sc};
        float2 v3 = {acc[slot][6]*sc, acc[slot][7]*sc};
        *(float2*)&Cr[base]   = v0; *(float2*)&Cr[base+2] = v1;
        *(float2*)&Ci[base]   = v2; *(float2*)&Ci[base+2] = v3;
      }
    }
  }
  __syncthreads();

  // P4: inverse DFT along omega with +-dy symmetry, single pass (225 units)
  float bestV = 3.0e38f; int bestP = 0;
  if (tid < 225) {
    int lt = tid % 25;          // lag tile: lagIdx l0..l0+3
    int dt = tid / 25;          // dy tile: dy0..dy0+5
    int l0 = 4*lt, dy0 = 6*dt;
    float su[4][6], sv[4][6];
    #pragma unroll
    for (int k = 0; k < 4; ++k)
      #pragma unroll
      for (int j = 0; j < 6; ++j) { su[k][j] = 0.f; sv[k][j] = 0.f; }
    const float* crp = Cr + l0;
    const float* cip = Ci + l0;
    const float* tp = g_P + 2*dy0;
    #pragma unroll 3
    for (int om2 = 0; om2 < NBIN; ++om2) {
      float2 c01 = *(const float2*)&crp[om2*CST2];
      float2 c23 = *(const float2*)&crp[om2*CST2 + 2];
      float2 i01 = *(const float2*)&cip[om2*CST2];
      float2 i23 = *(const float2*)&cip[om2*CST2 + 2];
      float4 t0 = *(const float4*)&tp[om2*128];
      float4 t1 = *(const float4*)&tp[om2*128 + 4];
      float4 t2 = *(const float4*)&tp[om2*128 + 8];
      float cc[4] = {c01.x, c01.y, c23.x, c23.y};
      float ii[4] = {i01.x, i01.y, i23.x, i23.y};
      float co[6] = {t0.x, t0.z, t1.x, t1.z, t2.x, t2.z};
      float si[6] = {t0.y, t0.w, t1.y, t1.w, t2.y, t2.w};
      #pragma unroll
      for (int k = 0; k < 4; ++k)
        #pragma unroll
        for (int j = 0; j < 6; ++j) {
          su[k][j] += cc[k]*co[j];
          sv[k][j] += ii[k]*si[j];
        }
    }
    #pragma unroll
    for (int k = 0; k < 4; ++k) {
      int lagIdx = l0 + k;          // lag = lagIdx - 49
      if (lagIdx <= 98) {
        int row = lagIdx + 1;       // lag + 50
        #pragma unroll
        for (int j = 0; j < 6; ++j) {
          int dy = dy0 + j;
          if (dy <= 49) {
            float vp = su[k][j] - sv[k][j];   // col = 50 + dy
            float vm = su[k][j] + sv[k][j];   // col = 50 - dy
            int posp = row*SD + (50 + dy);
            int posm = row*SD + (50 - dy);
            if (vp < bestV || (vp == bestV && posp < bestP)) { bestV = vp; bestP = posp; }
            if (vm < bestV || (vm == bestV && posm < bestP)) { bestV = vm; bestP = posm; }
          }
        }
      }
    }
  }
  __syncthreads();

  // block min-reduce (lexicographic (val, pos))
  sRedV[tid] = bestV; sRedP[tid] = bestP;
  __syncthreads();
  for (int off = 128; off > 0; off >>= 1) {
    if (tid < off) {
      float v2 = sRedV[tid+off]; int p2 = sRedP[tid+off];
      if (v2 < sRedV[tid] || (v2 == sRedV[tid] && p2 < sRedP[tid])) {
        sRedV[tid] = v2; sRedP[tid] = p2;
      }
    }
    __syncthreads();
  }
  if (tid == 0) { g_resV[bid] = sRedV[0]; g_resP[bid] = sRedP[0]; }
}

// ================= final: reduce over angles, emit outputs =================
__global__ void k_final(float* __restrict__ out) {
  int b = threadIdx.x;
  if (b >= NB) return;
  float bv = 0.f; int bp = 0; int ba = 0;
  for (int a = 0; a < NANG; ++a) {
    float v = g_resV[b*NANG + a];
    if (v < bv) { bv = v; bp = g_resP[b*NANG + a]; ba = a; }
  }
  out[b] = 0.05235987755982988f * (float)ba;
  out[NB + 2*b]     = (float)(bp / SD) - 50.f;
  out[NB + 2*b + 1] = (float)(bp % SD) - 50.f;
}

extern "C" void kernel_launch(void* const* d_in, const int* in_sizes, int n_in,
                              void* d_out, int out_size, void* d_ws, size_t ws_size,
                              hipStream_t stream) {
  const float* rec = (const float*)d_in[0];
  const float* lig = (const float*)d_in[1];
  const float* wr  = (const float*)d_in[2];
  const float* br  = (const float*)d_in[3];
  const float* wsc = (const float*)d_in[4];
  (void)in_sizes; (void)n_in; (void)out_size; (void)d_ws; (void)ws_size;
  hipLaunchKernelGGL(k_prep, dim3(NB+1), dim3(256), 0, stream, rec, lig, wr, br, wsc);
  hipLaunchKernelGGL(k_main, dim3(NANG*NB), dim3(256), 0, stream);
  hipLaunchKernelGGL(k_final, dim3(1), dim3(64), 0, stream, (float*)d_out);
}

// Round 5
// 329.894 us; speedup vs baseline: 1.8253x; 1.8253x over previous
//
#include <hip/hip_runtime.h>
#include <math.h>

#define NANG 120
#define NB   16
#define H    50
#define SD   100
#define NBIN 51        // rfft bins of length-100
#define PADB 3         // top pad rows of B-hat
#define BROWS 60       // stored rows: r in [-3, 56]
#define BST  106       // B-hat row stride
#define WST  104       // g_W row stride
#define RTST 52        // Rt row stride
#define CST  58        // C lag stride (per-half local lag index)
#define AX   58        // g_Arec x rows (50 real + 8 zero pad)

// ---- device-global scratch ----
__device__ __align__(16) float g_Arec[NB*2*AX*NBIN*2 + 64]; // [b][c][x][om][2], x 50..57 zero
__device__ __align__(16) float g_ligc[NB*2*H*H];            // [b][c][y][x]
__device__ __align__(16) float g_W[H*WST];                  // [y][2*om+p] = (cos, -sin)
__device__ __align__(16) float g_P[NBIN*128 + 64];          // [om][2*dy+p] = (cos,sin), dy 0..49
__device__ float g_resV[NANG*NB];
__device__ int   g_resP[NANG*NB];

// 8-wave cost-balanced P3 schedules (d0 bases; 127 = sentinel).
// h0 groups/wave: 6,6,5,5,5,5,5,5 ; h1: 7,7,7,7,7,7,7,0
__device__ const int g_s3[2][8][2] = {
  {{-5,127},{-9,127},{-13,127},{-17,127},{-21,-49},{-25,-45},{-29,-41},{-33,-37}},
  {{-1,127},{3,47},{7,43},{11,39},{15,35},{19,27},{23,31},{127,127}}
};

// ================= prep: conv+relu+combine, rec spectrum, tables =================
__global__ __launch_bounds__(512) void k_prep(const float* __restrict__ rec,
                                              const float* __restrict__ lig,
                                              const float* __restrict__ wr,
                                              const float* __restrict__ br,
                                              const float* __restrict__ wsc) {
  const int blk = blockIdx.x;
  const int tid = threadIdx.x;
  if (blk == NB) {
    for (int u = tid; u < H*WST; u += 512) {
      int y = u / WST, col = u % WST;
      float v = 0.f;
      if (col < 2*NBIN) {
        int om = col >> 1;
        int k = (om * y) % SD;
        double ang = 6.283185307179586 * (double)k / 100.0;
        v = (col & 1) ? (float)(-sin(ang)) : (float)cos(ang);
      }
      g_W[u] = v;
    }
    for (int u = tid; u < NBIN*128; u += 512) {
      int om = u >> 7, q = u & 127;
      int dy = q >> 1;
      float v = 0.f;
      if (dy <= 49) {
        int k = (om * dy) % SD;
        double ang = 6.283185307179586 * (double)k / 100.0;
        v = (q & 1) ? (float)sin(ang) : (float)cos(ang);
      }
      g_P[u] = v;
    }
    return;
  }
  const int b = blk;
  __shared__ float recf[2*H*H];
  __shared__ float tbl[SD*2];
  for (int k = tid; k < SD; k += 512) {
    double ang = 6.283185307179586 * (double)k / 100.0;
    tbl[2*k]   = (float)cos(ang);
    tbl[2*k+1] = (float)sin(ang);
  }
  const float* rimg = rec + b*H*H;
  const float* limg = lig + b*H*H;
  for (int p = tid; p < H*H; p += 512) {
    int i = p / H, j = p - (p/H)*H;
    float ar0 = br[0], ar1 = br[1], al0 = br[0], al1 = br[1];
    for (int di = 0; di < 3; ++di) {
      int ii = i + di - 1;
      if (ii < 0 || ii >= H) continue;
      for (int dj = 0; dj < 3; ++dj) {
        int jj = j + dj - 1;
        if (jj < 0 || jj >= H) continue;
        float rv = rimg[ii*H+jj], lv = limg[ii*H+jj];
        float w0 = wr[di*3 + dj], w1 = wr[9 + di*3 + dj];
        ar0 += w0*rv; ar1 += w1*rv; al0 += w0*lv; al1 += w1*lv;
      }
    }
    ar0 = fmaxf(ar0, 0.f); ar1 = fmaxf(ar1, 0.f);
    al0 = fmaxf(al0, 0.f); al1 = fmaxf(al1, 0.f);
    recf[p] = ar0; recf[H*H + p] = ar1;
    g_ligc[((b*2+0)*H + i)*H + j] = wsc[0]*al0 + wsc[1]*al1;
    g_ligc[((b*2+1)*H + i)*H + j] = wsc[2]*al0 + wsc[3]*al1;
  }
  for (int u = tid; u < 2*8*102; u += 512) {
    int c = u / 816; int r = u % 816;
    int x = 50 + r / 102; int q = r % 102;
    g_Arec[((b*2+c)*AX + x)*102 + q] = 0.f;
  }
  __syncthreads();
  for (int u = tid; u < 2*H*NBIN; u += 512) {
    int om = u % NBIN; int rest = u / NBIN; int x = rest % H; int c = rest / H;
    const float* row = recf + (c*H + x)*H;
    float sr = 0.f, si = 0.f;
    int k = 0;
    for (int y = 0; y < H; ++y) {
      float rv = row[y];
      sr += rv * tbl[2*k];
      si -= rv * tbl[2*k+1];
      k += om; if (k >= SD) k -= SD;
    }
    float* dst = g_Arec + ((b*2+c)*AX + x)*102 + 2*om;
    dst[0] = sr; dst[1] = si;
  }
}

#define P3_STEP(uu) do { \
  float Ar = ar_[(uu)&7], Ai = ai_[(uu)&7]; \
  { const int sl=(uu)&7;     c0 += Ar*br_[sl] + Ai*bi_[sl]; c4 += Ar*bi_[sl] - Ai*br_[sl]; } \
  { const int sl=((uu)+1)&7; c1 += Ar*br_[sl] + Ai*bi_[sl]; c5 += Ar*bi_[sl] - Ai*br_[sl]; } \
  { const int sl=((uu)+2)&7; c2 += Ar*br_[sl] + Ai*bi_[sl]; c6 += Ar*bi_[sl] - Ai*br_[sl]; } \
  { const int sl=((uu)+3)&7; c3 += Ar*br_[sl] + Ai*bi_[sl]; c7 += Ar*bi_[sl] - Ai*br_[sl]; } \
} while(0)

// ================= main: per (angle,batch) block, 512 threads =================
__global__ __launch_bounds__(512, 4) void k_main() {
  const int bid = blockIdx.x;
  const int a = bid % NANG;
  const int b = bid / NANG;
  const int tid = threadIdx.x;

  // LDS (words):
  //   [0..12720)       sB  [2ch][60][106]      live P2..end of P3(h1)
  //   [12720..17920)   Rt  [2][50][52]         dead after P2
  //   [12720..18636)   Cr/Ci [51][58] x2       written in P3 (after Rt dead)
  //   [18636..18652)   reduction (8+8)
  __shared__ __align__(16) float sMem[18652];
  float* sB = sMem;
  float* Rt = sMem + 12720;
  float* Cr = sMem + 12720;
  float* Ci = sMem + 12720 + NBIN*CST;
  float* sRedV = sMem + 18636;
  int*   sRedP = (int*)(sMem + 18644);

  // P0: zero pad rows of sB (rows 0..2 and 53..59, both channels)
  for (int u = tid; u < 2*10*BST; u += 512) {
    int ch = u / (10*BST);
    int r  = (u % (10*BST)) / BST;
    int col = u % BST;
    int row = (r < 3) ? r : r + 50;
    sB[ch*BROWS*BST + row*BST + col] = 0.f;
  }

  // P1: bilinear rotation of combined ligand features -> Rt (transposed)
  float angf = 0.05235987755982988f * (float)a;
  float ca = cosf(angf), sa = sinf(angf);
  const float* L0 = g_ligc + (b*2+0)*H*H;
  const float* L1 = g_ligc + (b*2+1)*H*H;
  for (int p = tid; p < H*H; p += 512) {
    int i = p / H, j = p - (p/H)*H;
    float gy = -1.f + (float)i*(2.f/49.f);
    float gx = -1.f + (float)j*(2.f/49.f);
    float x_in = ca*gx - sa*gy;
    float y_in = sa*gx + ca*gy;
    float px = (x_in + 1.f)*0.5f*49.f;
    float py = (y_in + 1.f)*0.5f*49.f;
    float fx = floorf(px), fy = floorf(py);
    int x0 = (int)fx, y0 = (int)fy;
    int x1 = x0 + 1, y1 = y0 + 1;
    float wx1 = px - fx, wx0 = 1.f - wx1;
    float wy1 = py - fy, wy0 = 1.f - wy1;
    float v0 = 0.f, v1 = 0.f;
    if (y0 >= 0 && y0 < H) {
      if (x0 >= 0 && x0 < H) { float w = wy0*wx0; int o = y0*H+x0; v0 += w*L0[o]; v1 += w*L1[o]; }
      if (x1 >= 0 && x1 < H) { float w = wy0*wx1; int o = y0*H+x1; v0 += w*L0[o]; v1 += w*L1[o]; }
    }
    if (y1 >= 0 && y1 < H) {
      if (x0 >= 0 && x0 < H) { float w = wy1*wx0; int o = y1*H+x0; v0 += w*L0[o]; v1 += w*L1[o]; }
      if (x1 >= 0 && x1 < H) { float w = wy1*wx1; int o = y1*H+x1; v0 += w*L0[o]; v1 += w*L1[o]; }
    }
    Rt[(0*H + j)*RTST + i] = v0;
    Rt[(1*H + j)*RTST + i] = v1;
  }
  __syncthreads();

  // P2: y-DFT of rotated rows -> sB, both channels, one round (442 units)
  if (tid < 442) {
    int c = tid / 221;
    int r = tid % 221;
    int cg = r % 17;            // col group (6 words), fast across lanes
    int it = r / 17;            // 0..12
    int i0 = it*4;
    int col0 = 6*cg;
    float pacc[4][6];
    #pragma unroll
    for (int p = 0; p < 4; ++p)
      #pragma unroll
      for (int q = 0; q < 6; ++q) pacc[p][q] = 0.f;
    const float* rtc = Rt + c*H*RTST + i0;
    const float* wt = g_W + col0;
    #pragma unroll 2
    for (int y = 0; y < H; ++y) {
      float4 rv = *(const float4*)&rtc[y*RTST];
      float ww[6];
      #pragma unroll
      for (int q = 0; q < 3; ++q) {
        float2 w2 = *(const float2*)&wt[y*WST + 2*q];
        ww[2*q] = w2.x; ww[2*q+1] = w2.y;
      }
      float rr[4] = {rv.x, rv.y, rv.z, rv.w};
      #pragma unroll
      for (int p = 0; p < 4; ++p)
        #pragma unroll
        for (int q = 0; q < 6; ++q) pacc[p][q] += rr[p]*ww[q];
    }
    float* dst = sB + c*BROWS*BST + col0;
    #pragma unroll
    for (int p = 0; p < 4; ++p) {
      int i = i0 + p;
      if (i < H) {
        #pragma unroll
        for (int q = 0; q < 3; ++q) {
          float2 o = {pacc[p][2*q], pacc[p][2*q+1]};
          *(float2*)&dst[(PADB+i)*BST + 2*q] = o;
        }
      }
    }
  }
  __syncthreads();

  const int wid = tid >> 6, lane = tid & 63;
  const int om = (lane <= 50) ? lane : 50;
  const bool omValid = (lane <= 50);
  float bestV = 3.0e38f; int bestP = 0;

  for (int h = 0; h < 2; ++h) {
    const int lagBase = h ? -1 : -49;

    // P3(h): per-bin complex correlation along x -> C (per-tile scalars only)
    #pragma unroll
    for (int slot = 0; slot < 2; ++slot) {
      const int d0 = g_s3[h][wid][slot];
      if (d0 != 127) {
        const int x_lo = max(0, -(d0+3));
        const int x_hi = min(H, H - d0);
        const int ng = (x_hi - x_lo + 7) >> 3;
        float c0=0,c1=0,c2=0,c3=0,c4=0,c5=0,c6=0,c7=0;
        #pragma unroll 1
        for (int c = 0; c < 2; ++c) {
          const float* Ap = g_Arec + ((b*2+c)*AX + x_lo)*102 + 2*om;
          const float* Bp = sB + c*BROWS*BST + (PADB + x_lo + d0)*BST + 2*om;
          float br_[8], bi_[8], ar_[8], ai_[8];
          #pragma unroll
          for (int s = 0; s < 8; ++s) {
            float2 bv = *(const float2*)&Bp[s*BST];
            br_[s] = bv.x; bi_[s] = bv.y;
            float2 av = *(const float2*)&Ap[s*102];
            ar_[s] = av.x; ai_[s] = av.y;
          }
          #pragma unroll 1
          for (int g = 0; g < ng-1; ++g) {
            #pragma unroll
            for (int u = 0; u < 8; ++u) {
              P3_STEP(u);
              float2 bv = *(const float2*)&Bp[(u+8)*BST];
              br_[u] = bv.x; bi_[u] = bv.y;
              float2 av = *(const float2*)&Ap[(u+8)*102];
              ar_[u] = av.x; ai_[u] = av.y;
            }
            Bp += 8*BST; Ap += 8*102;
          }
          {
            const int rowcap = 56 - (x_lo + 8*(ng-1) + d0);
            P3_STEP(0); P3_STEP(1); P3_STEP(2); P3_STEP(3); P3_STEP(4);
            #pragma unroll
            for (int s = 0; s < 3; ++s) {
              int o = min(8+s, rowcap);
              float2 bv = *(const float2*)&Bp[o*BST];
              br_[s] = bv.x; bi_[s] = bv.y;
            }
            P3_STEP(5); P3_STEP(6); P3_STEP(7);
          }
        }
        if (omValid) {
          const float sc = (om == 0 || om == 50) ? 0.5f : 1.0f;
          int base = om*CST + (d0 - lagBase);
          float2 v0 = {c0*sc, c1*sc}; *(float2*)&Cr[base]   = v0;
          float2 v1 = {c2*sc, c3*sc}; *(float2*)&Cr[base+2] = v1;
          float2 v2 = {c4*sc, c5*sc}; *(float2*)&Ci[base]   = v2;
          float2 v3 = {c6*sc, c7*sc}; *(float2*)&Ci[base+2] = v3;
        }
      }
    }
    __syncthreads();

    // P4(h): inverse DFT along omega with +-dy symmetry (2 lag x 3 dy tiles)
    {
      const int nLT = h ? 26 : 24;
      const int units = nLT * 17;
      const int gBase = h ? 48 : 0;
      if (tid < units) {
        int lt = tid % nLT;
        int dt = tid / nLT;
        int l0 = 2*lt, dy0 = 3*dt;
        float su[2][3], sv[2][3];
        #pragma unroll
        for (int k = 0; k < 2; ++k)
          #pragma unroll
          for (int j = 0; j < 3; ++j) { su[k][j] = 0.f; sv[k][j] = 0.f; }
        const float* crp = Cr + l0;
        const float* cip = Ci + l0;
        const float* tp = g_P + 2*dy0;
        #pragma unroll 3
        for (int om2 = 0; om2 < NBIN; ++om2) {
          float2 cv = *(const float2*)&crp[om2*CST];
          float2 iv = *(const float2*)&cip[om2*CST];
          float2 t0 = *(const float2*)&tp[om2*128];
          float2 t1 = *(const float2*)&tp[om2*128 + 2];
          float2 t2 = *(const float2*)&tp[om2*128 + 4];
          float cc[2] = {cv.x, cv.y};
          float ii[2] = {iv.x, iv.y};
          float co[3] = {t0.x, t1.x, t2.x};
          float si[3] = {t0.y, t1.y, t2.y};
          #pragma unroll
          for (int k = 0; k < 2; ++k)
            #pragma unroll
            for (int j = 0; j < 3; ++j) {
              su[k][j] += cc[k]*co[j];
              sv[k][j] += ii[k]*si[j];
            }
        }
        #pragma unroll
        for (int k = 0; k < 2; ++k) {
          int lagIdx = gBase + l0 + k;
          if (lagIdx <= 98) {
            int row = lagIdx + 1;
            #pragma unroll
            for (int j = 0; j < 3; ++j) {
              int dy = dy0 + j;
              if (dy <= 49) {
                float vp = su[k][j] - sv[k][j];   // col = 50 + dy
                float vm = su[k][j] + sv[k][j];   // col = 50 - dy
                int posp = row*SD + (50 + dy);
                int posm = row*SD + (50 - dy);
                if (vp < bestV || (vp == bestV && posp < bestP)) { bestV = vp; bestP = posp; }
                if (vm < bestV || (vm == bestV && posm < bestP)) { bestV = vm; bestP = posm; }
              }
            }
          }
        }
      }
    }
    __syncthreads();
  }

  // reduce: wave shuffle lex-min, then 8-entry LDS final
  #pragma unroll
  for (int off = 32; off > 0; off >>= 1) {
    float v2 = __shfl_xor(bestV, off, 64);
    int   p2 = __shfl_xor(bestP, off, 64);
    if (v2 < bestV || (v2 == bestV && p2 < bestP)) { bestV = v2; bestP = p2; }
  }
  if (lane == 0) { sRedV[wid] = bestV; sRedP[wid] = bestP; }
  __syncthreads();
  if (tid == 0) {
    float bv = sRedV[0]; int bp = sRedP[0];
    for (int w = 1; w < 8; ++w) {
      float v2 = sRedV[w]; int p2 = sRedP[w];
      if (v2 < bv || (v2 == bv && p2 < bp)) { bv = v2; bp = p2; }
    }
    g_resV[bid] = bv; g_resP[bid] = bp;
  }
}

// ================= final: reduce over angles, emit outputs =================
__global__ void k_final(float* __restrict__ out) {
  int b = threadIdx.x;
  if (b >= NB) return;
  float bv = 0.f; int bp = 0; int ba = 0;
  for (int a = 0; a < NANG; ++a) {
    float v = g_resV[b*NANG + a];
    if (v < bv) { bv = v; bp = g_resP[b*NANG + a]; ba = a; }
  }
  out[b] = 0.05235987755982988f * (float)ba;
  out[NB + 2*b]     = (float)(bp / SD) - 50.f;
  out[NB + 2*b + 1] = (float)(bp % SD) - 50.f;
}

extern "C" void kernel_launch(void* const* d_in, const int* in_sizes, int n_in,
                              void* d_out, int out_size, void* d_ws, size_t ws_size,
                              hipStream_t stream) {
  const float* rec = (const float*)d_in[0];
  const float* lig = (const float*)d_in[1];
  const float* wr  = (const float*)d_in[2];
  const float* br  = (const float*)d_in[3];
  const float* wsc = (const float*)d_in[4];
  (void)in_sizes; (void)n_in; (void)out_size; (void)d_ws; (void)ws_size;
  hipLaunchKernelGGL(k_prep, dim3(NB+1), dim3(512), 0, stream, rec, lig, wr, br, wsc);
  hipLaunchKernelGGL(k_main, dim3(NANG*NB), dim3(512), 0, stream);
  hipLaunchKernelGGL(k_final, dim3(1), dim3(64), 0, stream, (float*)d_out);
}